// Round 1
// baseline (457.846 us; speedup 1.0000x reference)
//
#include <hip/hip_runtime.h>
#include <stdint.h>

// LoRA: out[m,n] = sum_k x[m,k]*W[n,k] + sum_r y[m,r]*A[n,r],  y = x @ B^T
// M=256, N=8192, K=8192, R=16. All inputs fp32; compute in bf16 MFMA (thr 0.18).

#define DM 256
#define DK 8192
#define DN 8192
#define RLORA 16

#define TN 64
#define BK 64
#define KSPLIT 4
#define KCHUNK (DK / KSPLIT)   // 2048
#define NITER (KCHUNK / BK)    // 32

typedef short bf16x8 __attribute__((ext_vector_type(8)));   // 8 bf16 = 4 VGPRs
typedef float f32x4v __attribute__((ext_vector_type(4)));   // MFMA acc

typedef __attribute__((address_space(1))) const unsigned char glbc_u8;
typedef __attribute__((address_space(3))) unsigned char lds_u8;

__device__ __forceinline__ unsigned short f2bf(float f) {
  unsigned u = __builtin_bit_cast(unsigned, f);
  u += 0x7FFFu + ((u >> 16) & 1u);           // round-to-nearest-even
  return (unsigned short)(u >> 16);
}

// ---------------------------------------------------------------------------
// Prep 1: x -> bf16 (ws), and y = x @ B^T -> bf16 zero-padded to 64 cols.
// One block per m-row; 256 threads.
__global__ __launch_bounds__(256) void prep_x_y(
    const float* __restrict__ x, const float* __restrict__ Bm,
    unsigned short* __restrict__ xb, unsigned short* __restrict__ yb) {
  const int m = blockIdx.x;
  const int tid = threadIdx.x;
  const float4* xrow = (const float4*)(x + (size_t)m * DK);
  unsigned short* xbrow = xb + (size_t)m * DK;
  float acc[RLORA];
#pragma unroll
  for (int r = 0; r < RLORA; ++r) acc[r] = 0.f;
  for (int j = tid; j < DK / 4; j += 256) {     // 8 iterations
    float4 v = xrow[j];
    ushort4 h;
    h.x = f2bf(v.x); h.y = f2bf(v.y); h.z = f2bf(v.z); h.w = f2bf(v.w);
    *(ushort4*)(xbrow + j * 4) = h;
#pragma unroll
    for (int r = 0; r < RLORA; ++r) {
      float4 b = ((const float4*)(Bm + (size_t)r * DK))[j];
      acc[r] += v.x * b.x + v.y * b.y + v.z * b.z + v.w * b.w;
    }
  }
  __shared__ float red[256 * RLORA];
#pragma unroll
  for (int r = 0; r < RLORA; ++r) red[tid * RLORA + r] = acc[r];
  __syncthreads();
  for (int off = 128; off >= 1; off >>= 1) {
    if (tid < off) {
#pragma unroll
      for (int r = 0; r < RLORA; ++r)
        red[tid * RLORA + r] += red[(tid + off) * RLORA + r];
    }
    __syncthreads();
  }
  if (tid < 64)
    yb[m * 64 + tid] = (tid < RLORA) ? f2bf(red[tid]) : (unsigned short)0;
}

// ---------------------------------------------------------------------------
// Prep 2: A[n][16] fp32 -> A_bf16[n][64] zero-padded.  grid 512 x 256.
__global__ __launch_bounds__(256) void prep_A(
    const float* __restrict__ A, unsigned short* __restrict__ Ab) {
  const int base = blockIdx.x * 1024 + threadIdx.x;
#pragma unroll
  for (int i = 0; i < 4; ++i) {
    int e = base + i * 256;                     // 0 .. 524287
    int n = e >> 6, c = e & 63;
    Ab[e] = (c < RLORA) ? f2bf(A[n * RLORA + c]) : (unsigned short)0;
  }
}

// ---------------------------------------------------------------------------
// Main GEMM: block tile 256(m) x 64(n), BK=64, split-K=4, atomic fp32 epilogue.
// grid (128, 4); 256 threads = 4 waves stacked in m (wave tile 64x64).
// LDS frag-linear layout: chunk idx = ((g*2+s)*4+c)*16+r  (g=16-row group,
// s=k-step of 32, c=k-octet, r=row) -> ds_read_b128 at lane*16 (conflict-free)
// and global_load_lds-compatible (wave-uniform base + lane*16).
__global__ __launch_bounds__(256, 2) void lora_gemm(
    const unsigned short* __restrict__ xb,   // [256][8192] bf16
    const float* __restrict__ W,             // [8192][8192] fp32
    const unsigned short* __restrict__ yb,   // [256][64] bf16, padded
    const unsigned short* __restrict__ Ab,   // [8192][64] bf16, padded
    float* __restrict__ out) {               // [256][8192] fp32, pre-zeroed
  __shared__ unsigned short xs[DM * BK];   // 32 KB x-tile
  __shared__ unsigned short wt[TN * BK];   // 8 KB  W-tile

  const int tid = threadIdx.x;
  const int lane = tid & 63;
  const int wave = tid >> 6;                 // 0..3 = m quadrant
  const int n_base = blockIdx.x * TN;        // 0..8128
  const int kz = blockIdx.y;                 // 0..3
  const int k_base = kz * KCHUNK;

  f32x4v acc[4][4];
#pragma unroll
  for (int mi = 0; mi < 4; ++mi)
#pragma unroll
    for (int ni = 0; ni < 4; ++ni) acc[mi][ni] = {0.f, 0.f, 0.f, 0.f};

  // Precompute per-thread staging pointers (k-invariant decode, hoisted).
  const unsigned short* xgp[8];
#pragma unroll
  for (int j = 0; j < 8; ++j) {
    int idx = wave * 512 + j * 64 + lane;    // 2048 chunks of 16B
    int r = idx & 15, c = (idx >> 4) & 3, s = (idx >> 6) & 1, g = idx >> 7;
    xgp[j] = xb + (size_t)(g * 16 + r) * DK + k_base + s * 32 + c * 8;
  }
  const float4* wgp[2];
  unsigned wlds[2];
#pragma unroll
  for (int j = 0; j < 2; ++j) {
    int idx = j * 256 + tid;                 // 512 chunks of 16B
    int r = idx & 15, c = (idx >> 4) & 3, s = (idx >> 6) & 1, g = idx >> 7;
    wgp[j] = (const float4*)(W + (size_t)(n_base + g * 16 + r) * DK +
                             k_base + s * 32 + c * 8);
    wlds[j] = idx * 16;
  }

  const int niter = (kz == 0) ? NITER + 1 : NITER;  // kz 0 appends LoRA iter

  for (int it = 0; it < niter; ++it) {
    const bool lora = (it == NITER);
    if (!lora) {
      // W fp32 loads first (longest latency chain through VGPRs)
      float4 wv0[2], wv1[2];
#pragma unroll
      for (int j = 0; j < 2; ++j) { wv0[j] = wgp[j][0]; wv1[j] = wgp[j][1]; wgp[j] += BK / 4; }
      // x: async global->LDS, 16B/lane
#pragma unroll
      for (int j = 0; j < 8; ++j) {
        __builtin_amdgcn_global_load_lds(
            (glbc_u8*)xgp[j],
            (lds_u8*)((char*)xs + (wave * 512 + j * 64) * 16), 16, 0, 0);
        xgp[j] += BK;
      }
      // W: convert + pack + ds_write_b128
#pragma unroll
      for (int j = 0; j < 2; ++j) {
        uint4 p;
        p.x = (unsigned)f2bf(wv0[j].x) | ((unsigned)f2bf(wv0[j].y) << 16);
        p.y = (unsigned)f2bf(wv0[j].z) | ((unsigned)f2bf(wv0[j].w) << 16);
        p.z = (unsigned)f2bf(wv1[j].x) | ((unsigned)f2bf(wv1[j].y) << 16);
        p.w = (unsigned)f2bf(wv1[j].z) | ((unsigned)f2bf(wv1[j].w) << 16);
        *(uint4*)((char*)wt + wlds[j]) = p;
      }
    } else {
      // LoRA iteration: x-tile <- y_bf16 (stride 64), W-tile <- A_bf16 (stride 64)
#pragma unroll
      for (int j = 0; j < 8; ++j) {
        int idx = wave * 512 + j * 64 + lane;
        int r = idx & 15, c = (idx >> 4) & 3, s = (idx >> 6) & 1, g = idx >> 7;
        const unsigned short* gp = yb + (g * 16 + r) * 64 + s * 32 + c * 8;
        __builtin_amdgcn_global_load_lds(
            (glbc_u8*)gp, (lds_u8*)((char*)xs + (wave * 512 + j * 64) * 16), 16, 0, 0);
      }
#pragma unroll
      for (int j = 0; j < 2; ++j) {
        int idx = wave * 128 + j * 64 + lane;
        int r = idx & 15, c = (idx >> 4) & 3, s = (idx >> 6) & 1, g = idx >> 7;
        const unsigned short* gp = Ab + (size_t)(n_base + g * 16 + r) * 64 + s * 32 + c * 8;
        __builtin_amdgcn_global_load_lds(
            (glbc_u8*)gp, (lds_u8*)((char*)wt + (wave * 128 + j * 64) * 16), 16, 0, 0);
      }
    }
    __syncthreads();   // compiler drains vmcnt here (global_load_lds landed)

#pragma unroll
    for (int s = 0; s < 2; ++s) {
      bf16x8 a[4], b[4];
#pragma unroll
      for (int mi = 0; mi < 4; ++mi) {
        int g = wave * 4 + mi;
        a[mi] = *(const bf16x8*)((const char*)xs + ((g * 2 + s) * 64 + lane) * 16);
      }
#pragma unroll
      for (int ni = 0; ni < 4; ++ni)
        b[ni] = *(const bf16x8*)((const char*)wt + ((ni * 2 + s) * 64 + lane) * 16);
#pragma unroll
      for (int mi = 0; mi < 4; ++mi)
#pragma unroll
        for (int ni = 0; ni < 4; ++ni)
          acc[mi][ni] = __builtin_amdgcn_mfma_f32_16x16x32_bf16(
              a[mi], b[ni], acc[mi][ni], 0, 0, 0);
    }
    __syncthreads();
  }

  // Epilogue: C/D layout col=lane&15, row=(lane>>4)*4+reg  [m89-verified]
  const int row0 = (lane >> 4) * 4;
  const int col = lane & 15;
#pragma unroll
  for (int mi = 0; mi < 4; ++mi)
#pragma unroll
    for (int ni = 0; ni < 4; ++ni)
#pragma unroll
      for (int rg = 0; rg < 4; ++rg) {
        int m = wave * 64 + mi * 16 + row0 + rg;
        int n = n_base + ni * 16 + col;
        atomicAdd(out + (size_t)m * DN + n, acc[mi][ni][rg]);
      }
}

// ---------------------------------------------------------------------------
extern "C" void kernel_launch(void* const* d_in, const int* in_sizes, int n_in,
                              void* d_out, int out_size, void* d_ws, size_t ws_size,
                              hipStream_t stream) {
  const float* x  = (const float*)d_in[0];   // [4,64,8192]
  const float* W  = (const float*)d_in[1];   // [8192,8192]
  const float* A  = (const float*)d_in[2];   // [8192,16]
  const float* Bm = (const float*)d_in[3];   // [16,8192]
  float* out = (float*)d_out;                // [4,64,8192] fp32

  unsigned short* xb = (unsigned short*)d_ws;          // 4 MiB
  unsigned short* yb = xb + (size_t)DM * DK;           // 32 KiB
  unsigned short* Ab = yb + (size_t)DM * 64;           // 1 MiB

  hipMemsetAsync(d_out, 0, (size_t)out_size * sizeof(float), stream);
  prep_x_y<<<DM, 256, 0, stream>>>(x, Bm, xb, yb);
  prep_A<<<512, 256, 0, stream>>>(A, Ab);
  lora_gemm<<<dim3(DN / TN, KSPLIT), 256, 0, stream>>>(xb, W, yb, Ab, out);
}